// Round 1
// baseline (2256.659 us; speedup 1.0000x reference)
//
#include <hip/hip_runtime.h>
#include <math.h>

#define NBATCH 256
#define NT 256
#define DZ 32
#define DA 16
#define DU 8
#define NK 4
#define NH 64
#define NG 192   // 3*NH
#define PAD 36   // padded row stride for 32-wide matrices (float4-aligned, conflict-friendly)

// output offsets in floats: (z, mu, Sig, a, A_t, B_t, C_t), each (256,256,...)
#define Z_OFF    0ll
#define MU_OFF   2097152ll
#define SIG_OFF  4194304ll
#define AA_OFF   71303168ll   // a_t
#define A_OUT    72351744ll
#define B_OUT    139460608ll
#define C_OUT    156237824ll

__global__ __launch_bounds__(512, 2) void lgssm_scan_kernel(
    const float* __restrict__ mu0,  const float* __restrict__ Sig0,
    const float* __restrict__ alpha0,const float* __restrict__ h0,
    const float* __restrict__ u_f,  const float* __restrict__ eps_g,
    const float* __restrict__ Ag,   const float* __restrict__ Bg,
    const float* __restrict__ Cg,   const float* __restrict__ Qg,
    const float* __restrict__ Wxg,  const float* __restrict__ Whg,
    const float* __restrict__ bxg,  const float* __restrict__ bhg,
    const float* __restrict__ Wog,  const float* __restrict__ bog,
    float* __restrict__ out)
{
    const int tid  = threadIdx.x;
    const int b    = blockIdx.x;
    const int lane = tid & 63;
    const int wid  = tid >> 6;

    __shared__ __attribute__((aligned(16))) float sQ[DZ*DZ];
    __shared__ __attribute__((aligned(16))) float sWo[NH*NK];
    __shared__ float sbx[NG], sbh[NG], sbo[NK];
    __shared__ __attribute__((aligned(16))) float sAtT[DZ*PAD]; // sAtT[k*PAD+i] = At[i][k]
    __shared__ __attribute__((aligned(16))) float sTT[DZ*PAD];  // sTT[k*PAD+i] = T[i][k]
    __shared__ __attribute__((aligned(16))) float sSA[DZ*PAD];  // Sigma ping
    __shared__ __attribute__((aligned(16))) float sSB[DZ*PAD];  // Sigma pong
    __shared__ float sBt[DZ*9];    // padded stride 9
    __shared__ float sCt[DA*33];   // padded stride 33
    __shared__ float smu[DZ], sze[DZ], sz[DZ];
    __shared__ float sh[NH];
    __shared__ float salpha[NK];
    __shared__ float seps[DZ];
    __shared__ float su[DU];
    __shared__ float sgx[NG], sgh[NG];
    __shared__ float sred[384];

    // ---------- register-resident static weights ----------
    float Areg0[NK], Areg1[NK];  // A[k][2tid], A[k][2tid+1]
    float Breg[NK];              // tid<256: B[k][tid]
    float Creg[NK];              // C[k][tid]
    float Whreg[32];             // tid in [128,512): Wh[(jh*32+jj)][g], g=(tid-128)>>1, jh=(tid-128)&1
    float Wxreg[32];             // tid<192: Wx[i][tid]

    const int e0 = 2*tid, e1 = 2*tid + 1;
    #pragma unroll
    for (int k = 0; k < NK; ++k) {
        Areg0[k] = Ag[k*1024 + e0];
        Areg1[k] = Ag[k*1024 + e1];
        Creg[k]  = Cg[k*512 + tid];
        Breg[k]  = (tid < 256) ? Bg[k*256 + tid] : 0.f;
    }
    if (tid >= 128) {
        int tp = tid - 128, g = tp >> 1, jh = tp & 1;
        #pragma unroll
        for (int jj = 0; jj < 32; ++jj)
            Whreg[jj] = Whg[(jh*32 + jj)*NG + g];
    }
    if (tid < NG) {
        #pragma unroll
        for (int i = 0; i < 32; ++i)
            Wxreg[i] = Wxg[i*NG + tid];
    }

    // ---------- one-time LDS init ----------
    sQ[e0] = Qg[e0]; sQ[e1] = Qg[e1];
    if (tid < NH*NK) sWo[tid] = Wog[tid];
    if (tid < NG) { sbx[tid] = bxg[tid]; sbh[tid] = bhg[tid]; }
    if (tid < NK) { sbo[tid] = bog[tid]; salpha[tid] = alpha0[b*NK + tid]; }
    if (tid < DZ) smu[tid] = mu0[b*DZ + tid];
    if (tid < NH) sh[tid]  = h0[b*NH + tid];
    {
        int i0 = e0 >> 5, j0 = e0 & 31;
        float2 v = *(const float2*)&Sig0[b*1024 + e0];
        sSA[i0*PAD + j0]     = v.x;
        sSA[i0*PAD + j0 + 1] = v.y;
    }
    __syncthreads();

    const long long ob = (long long)b * NT;

    #pragma unroll 1
    for (int t = 0; t < NT; ++t) {
        float* Sc = (t & 1) ? sSB : sSA;
        float* Sn = (t & 1) ? sSA : sSB;
        const long long idx = ob + t;

        // ---- P1: mixtures A_t/B_t/C_t (reg-resident bases), store them; load u_t, eps_t ----
        {
            float a0 = salpha[0], a1 = salpha[1], a2 = salpha[2], a3 = salpha[3];

            float v0 = Areg0[0]*a0 + Areg0[1]*a1 + Areg0[2]*a2 + Areg0[3]*a3;
            float v1 = Areg1[0]*a0 + Areg1[1]*a1 + Areg1[2]*a2 + Areg1[3]*a3;
            int ai = e0 >> 5, aj = e0 & 31;
            sAtT[aj*PAD + ai]     = v0;   // transposed store: sAtT[k][i]
            sAtT[(aj+1)*PAD + ai] = v1;
            *(float2*)&out[A_OUT + idx*1024 + e0] = make_float2(v0, v1);

            float cv = Creg[0]*a0 + Creg[1]*a1 + Creg[2]*a2 + Creg[3]*a3;
            sCt[(tid>>5)*33 + (tid&31)] = cv;
            out[C_OUT + idx*512 + tid] = cv;

            if (tid < 256) {
                float bv = Breg[0]*a0 + Breg[1]*a1 + Breg[2]*a2 + Breg[3]*a3;
                sBt[(tid>>3)*9 + (tid&7)] = bv;
                out[B_OUT + idx*256 + tid] = bv;
            }
            if (tid >= 448 && tid < 480) seps[tid-448] = eps_g[(long long)b*8192 + t*32 + (tid-448)];
            if (tid >= 480 && tid < 488) su[tid-480]   = u_f[(long long)b*2048 + t*8 + (tid-480)];
        }
        __syncthreads();

        // ---- P2a: T = A_t * Sigma  (wave w -> rows 4w..4w+3; K split over wave halves) ----
        {
            int jl = lane & 31, kh = lane >> 5;
            float acc0=0.f, acc1=0.f, acc2=0.f, acc3=0.f;
            #pragma unroll
            for (int kk = 0; kk < 16; ++kk) {
                int k = (kk<<1) | kh;
                float4 a4 = *(const float4*)&sAtT[k*PAD + 4*wid];  // broadcast b128
                float  bv = Sc[k*PAD + jl];                        // stride-1, 2-way (free)
                acc0 += a4.x*bv; acc1 += a4.y*bv; acc2 += a4.z*bv; acc3 += a4.w*bv;
            }
            acc0 += __shfl_xor(acc0, 32); acc1 += __shfl_xor(acc1, 32);
            acc2 += __shfl_xor(acc2, 32); acc3 += __shfl_xor(acc3, 32);
            if (lane < 32)
                *(float4*)&sTT[jl*PAD + 4*wid] = make_float4(acc0, acc1, acc2, acc3);
        }
        __syncthreads();

        // ---- P2b: Sigma_new = T * A_t^T + Q ; store Sigma output ----
        {
            int jl = lane & 31, kh = lane >> 5;
            float acc0=0.f, acc1=0.f, acc2=0.f, acc3=0.f;
            #pragma unroll
            for (int kk = 0; kk < 16; ++kk) {
                int k = (kk<<1) | kh;
                float4 a4 = *(const float4*)&sTT[k*PAD + 4*wid];
                float  bv = sAtT[k*PAD + jl];
                acc0 += a4.x*bv; acc1 += a4.y*bv; acc2 += a4.z*bv; acc3 += a4.w*bv;
            }
            acc0 += __shfl_xor(acc0, 32); acc1 += __shfl_xor(acc1, 32);
            acc2 += __shfl_xor(acc2, 32); acc3 += __shfl_xor(acc3, 32);
            if (lane < 32) {
                float v0 = acc0 + sQ[(4*wid+0)*32 + jl];
                float v1 = acc1 + sQ[(4*wid+1)*32 + jl];
                float v2 = acc2 + sQ[(4*wid+2)*32 + jl];
                float v3 = acc3 + sQ[(4*wid+3)*32 + jl];
                Sn[(4*wid+0)*PAD + jl] = v0;
                Sn[(4*wid+1)*PAD + jl] = v1;
                Sn[(4*wid+2)*PAD + jl] = v2;
                Sn[(4*wid+3)*PAD + jl] = v3;
                long long sb = SIG_OFF + idx*1024;
                out[sb + (4*wid+0)*32 + jl] = v0;
                out[sb + (4*wid+1)*32 + jl] = v1;
                out[sb + (4*wid+2)*32 + jl] = v2;
                out[sb + (4*wid+3)*32 + jl] = v3;
            }
        }
        __syncthreads();

        // ---- P3: wave0 = sqrt-free LDL Cholesky + (L @ eps) via readlane;
        //          wave1 = mu update; waves2-7 = gh partials (h @ Wh) ----
        if (wid == 0) {
            int i = lane & 31;
            float s[32];
            #pragma unroll
            for (int c = 0; c < 32; c += 4) {
                float4 r4 = *(const float4*)&Sn[i*PAD + c];
                s[c] = r4.x; s[c+1] = r4.y; s[c+2] = r4.z; s[c+3] = r4.w;
            }
            float ze = 0.f;
            #pragma unroll
            for (int j = 0; j < 32; ++j) {
                float dj  = __int_as_float(__builtin_amdgcn_readlane(__float_as_int(s[j]), j));
                float rsq = rsqrtf(dj);
                float inv = rsq * rsq;              // 1/dj
                float wj  = rsq * seps[j];
                float contrib = s[j] * wj;          // = L[i][j] * eps[j] for i>=j
                ze += (i >= j) ? contrib : 0.f;
                float f = s[j] * inv;
                #pragma unroll
                for (int k = j+1; k < 32; ++k) {
                    float tk = __int_as_float(__builtin_amdgcn_readlane(__float_as_int(s[j]), k));
                    s[k] -= f * tk;                 // symmetric Schur update
                }
            }
            if (lane < 32) sze[i] = ze;
        } else if (wid == 1) {
            if (lane < 32) {
                int i = lane;
                float acc = 0.f;
                #pragma unroll
                for (int j = 0; j < 32; ++j) acc += sAtT[j*PAD + i] * smu[j];
                #pragma unroll
                for (int j = 0; j < 8; ++j)  acc += sBt[i*9 + j] * su[j];
                smu[i] = acc;                       // in-wave in-place is safe
                out[MU_OFF + idx*32 + i] = acc;
            }
        } else {
            int tp = tid - 128, jh = tp & 1;
            float acc = 0.f;
            #pragma unroll
            for (int jj = 0; jj < 32; ++jj) acc += Whreg[jj] * sh[jh*32 + jj];
            sred[tp] = acc;
        }
        __syncthreads();

        // ---- P4: z = mu + ze (store z); combine gh halves ----
        if (wid == 0) {
            if (lane < 32) {
                float zv = smu[lane] + sze[lane];
                sz[lane] = zv;
                out[Z_OFF + idx*32 + lane] = zv;
            }
        } else if (tid >= 64 && tid < 256) {
            int g = tid - 64;
            sgh[g] = sred[2*g] + sred[2*g+1] + sbh[g];
        }
        __syncthreads();

        // ---- P5: gx = z @ Wx + bx ; a_t = C_t @ z (store a) ----
        if (tid < NG) {
            float acc = sbx[tid];
            #pragma unroll
            for (int i2 = 0; i2 < 32; ++i2) acc += Wxreg[i2] * sz[i2];
            sgx[tid] = acc;
        } else if (wid == 7 && lane < 16) {
            int i = lane;
            float acc = 0.f;
            #pragma unroll
            for (int j = 0; j < 32; ++j) acc += sCt[i*33 + j] * sz[j];
            out[AA_OFF + idx*16 + i] = acc;
        }
        __syncthreads();

        // ---- P6+7: GRU gate combine, h update, logits + softmax -> alpha (wave 0) ----
        if (wid == 0) {
            int j = lane;
            float xr = sgx[j],      hr  = sgh[j];
            float xz = sgx[64+j],   hz  = sgh[64+j];
            float xn = sgx[128+j],  hng = sgh[128+j];
            float r    = 1.f / (1.f + expf(-(xr + hr)));
            float zg   = 1.f / (1.f + expf(-(xz + hz)));
            float n    = tanhf(xn + r * hng);
            float hnew = (1.f - zg) * n + zg * sh[j];
            sh[j] = hnew;
            float4 wo4 = *(const float4*)&sWo[j*4];
            float p0 = hnew*wo4.x, p1 = hnew*wo4.y, p2 = hnew*wo4.z, p3 = hnew*wo4.w;
            #pragma unroll
            for (int off = 32; off >= 1; off >>= 1) {
                p0 += __shfl_xor(p0, off);
                p1 += __shfl_xor(p1, off);
                p2 += __shfl_xor(p2, off);
                p3 += __shfl_xor(p3, off);
            }
            float o0 = p0 + sbo[0], o1 = p1 + sbo[1], o2 = p2 + sbo[2], o3 = p3 + sbo[3];
            float m  = fmaxf(fmaxf(o0, o1), fmaxf(o2, o3));
            float q0 = expf(o0 - m), q1 = expf(o1 - m), q2 = expf(o2 - m), q3 = expf(o3 - m);
            float sinv = 1.f / (q0 + q1 + q2 + q3);
            if (lane == 0) {
                salpha[0] = q0*sinv; salpha[1] = q1*sinv;
                salpha[2] = q2*sinv; salpha[3] = q3*sinv;
            }
        }
        __syncthreads();
    }
}

extern "C" void kernel_launch(void* const* d_in, const int* in_sizes, int n_in,
                              void* d_out, int out_size, void* d_ws, size_t ws_size,
                              hipStream_t stream) {
    lgssm_scan_kernel<<<dim3(NBATCH), dim3(512), 0, stream>>>(
        (const float*)d_in[0],  (const float*)d_in[1],  (const float*)d_in[2],
        (const float*)d_in[3],  (const float*)d_in[4],  (const float*)d_in[5],
        (const float*)d_in[6],  (const float*)d_in[7],  (const float*)d_in[8],
        (const float*)d_in[9],  (const float*)d_in[10], (const float*)d_in[11],
        (const float*)d_in[12], (const float*)d_in[13], (const float*)d_in[14],
        (const float*)d_in[15], (float*)d_out);
}